// Round 7
// baseline (200.454 us; speedup 1.0000x reference)
//
#include <hip/hip_runtime.h>
#include <stdint.h>

typedef int int32x4 __attribute__((ext_vector_type(4)));

constexpr int K_DIM = 4096;   // D_IN
constexpr int N_DIM = 4096;   // D_OUT
constexpr float QMAXF = 127.0f;

// ---------------------------------------------------------------------------
// Kernel 1: per-token dynamic absmax quantization (HBM-bound, ~unchanged)
// ---------------------------------------------------------------------------
__global__ __launch_bounds__(256) void quant_rows(const float* __restrict__ x,
                                                  int8_t* __restrict__ q,
                                                  float* __restrict__ scales) {
    const int row = blockIdx.x;
    const int tid = threadIdx.x;
    const size_t base = (size_t)row * K_DIM;

    const float4* xv = reinterpret_cast<const float4*>(x + base);
    float4 v[4];
#pragma unroll
    for (int i = 0; i < 4; ++i) v[i] = xv[tid + 256 * i];

    float m = 0.0f;
#pragma unroll
    for (int i = 0; i < 4; ++i)
        m = fmaxf(m, fmaxf(fmaxf(fabsf(v[i].x), fabsf(v[i].y)),
                           fmaxf(fabsf(v[i].z), fabsf(v[i].w))));
#pragma unroll
    for (int off = 32; off > 0; off >>= 1) m = fmaxf(m, __shfl_xor(m, off));

    __shared__ float wmax[4];
    if ((tid & 63) == 0) wmax[tid >> 6] = m;
    __syncthreads();
    const float am = fmaxf(fmaxf(wmax[0], wmax[1]), fmaxf(wmax[2], wmax[3]));
    const float scale = fmaxf(am * (1.0f / 127.0f), 1e-8f);
    if (tid == 0) scales[row] = scale;
    const float inv = 1.0f / scale;

    int* qw = reinterpret_cast<int*>(q + base);
#pragma unroll
    for (int i = 0; i < 4; ++i) {
        float f0 = fminf(QMAXF, fmaxf(-QMAXF, rintf(v[i].x * inv)));
        float f1 = fminf(QMAXF, fmaxf(-QMAXF, rintf(v[i].y * inv)));
        float f2 = fminf(QMAXF, fmaxf(-QMAXF, rintf(v[i].z * inv)));
        float f3 = fminf(QMAXF, fmaxf(-QMAXF, rintf(v[i].w * inv)));
        int b0 = ((int)f0) & 255, b1 = ((int)f1) & 255;
        int b2 = ((int)f2) & 255, b3 = ((int)f3) & 255;
        qw[tid + 256 * i] = b0 | (b1 << 8) | (b2 << 16) | (b3 << 24);
    }
}

// ---------------------------------------------------------------------------
// Kernel 2: pack int32 weight buffer -> int8 (HBM-bound)
// ---------------------------------------------------------------------------
__global__ __launch_bounds__(256) void pack_w(const int* __restrict__ w,
                                              int8_t* __restrict__ w8) {
    const int idx = blockIdx.x * 256 + threadIdx.x;
    const int4 v = reinterpret_cast<const int4*>(w)[idx];
    int packed = (v.x & 255) | ((v.y & 255) << 8) | ((v.z & 255) << 16) | ((v.w & 255) << 24);
    reinterpret_cast<int*>(w8)[idx] = packed;
}

// ---------------------------------------------------------------------------
// Kernel 3: int8 GEMM, m201-faithful balanced phases.
// 256x256 tile, BK=64, 8 waves (2Mx4N), ring-4 LDS (128 KB), prefetch
// distance 3, 2 phases/K-tile:
//   P0: 2 GLL (A,t+3) | 8 ds_read (A[0-3],B[0-3]) | bar | lgkm0 | 16 MFMA | bar
//   P1: 2 GLL (B,t+3) | 4 ds_read (A[4-7])        | bar | lgkm0 | 16 MFMA |
//       vmcnt(8) | bar
// vmcnt ledger (issue order per tile: A0,A1,B0,B1): at end-of-tile-t gate,
// outstanding = tiles t+2,t+3 (8 loads) => vmcnt(8) guarantees t+1 landed.
// Never drains in steady state. Tail: t==NT-3 -> 4, t>=NT-2 -> 0.
// WAR: GLL(t+3) targets ring slot (t-1)&3; every wave drained its reads of
// that slot (phase lgkmcnt(0)) before the end-of-(t-1) barrier. Safe.
// LDS swizzle (round-2 verified, 0 conflicts): LDS[r][sl] holds granule
// sl^((r>>1)&3), staged via pre-swizzled global source (linear LDS dest);
// read at sl = ls ^ ((l15>>1)&3).
// ---------------------------------------------------------------------------
constexpr int BM = 256, BN = 256, BK = 64;
constexpr int NT = K_DIM / BK;     // 64 K-tiles

#define GLL(src, dst)                                                          \
    __builtin_amdgcn_global_load_lds(                                          \
        (const __attribute__((address_space(1))) unsigned int*)(src),          \
        (__attribute__((address_space(3))) unsigned int*)(dst), 16, 0, 0)

#define MFMA_I8(a, b, c) __builtin_amdgcn_mfma_i32_16x16x64_i8((a), (b), (c), 0, 0, 0)

__global__ __launch_bounds__(512, 2) void w8a8_gemm256(
        const int8_t* __restrict__ A, const int8_t* __restrict__ B,
        const float* __restrict__ asc, const float* __restrict__ wsc,
        float* __restrict__ C, int M) {
    extern __shared__ int8_t lds[];   // 128 KB: A ring @0 (4x16KB), B ring @65536

    const int tid  = threadIdx.x;
    const int lane = tid & 63;
    const int wave = tid >> 6;

    // XCD-aware bijective swizzle (nwg = 512, divisible by 8)
    const int nwg = gridDim.x;
    const int bid = blockIdx.x;
    const int swz = (bid & 7) * (nwg >> 3) + (bid >> 3);
    const int NB  = N_DIM / BN;       // 16
    const int brow = (swz / NB) * BM;
    const int bcol = (swz % NB) * BN;

    const int wm = wave >> 2;         // 0..1
    const int wn = wave & 3;          // 0..3
    const int l15 = lane & 15;
    const int ls  = lane >> 4;

    // ---- staging (per-lane pre-swizzled GLOBAL source, linear LDS dest) ----
    // seg s (0..1023): row = s>>2, slot = s&3, stored granule = (s&3)^((s>>3)&3)
    const int s0 = tid, s1 = tid + 512;
    const int r0s = s0 >> 2, g0 = (s0 & 3) ^ ((s0 >> 3) & 3);
    const int r1s = s1 >> 2, g1 = (s1 & 3) ^ ((s1 >> 3) & 3);
    const int8_t* gA0 = A + (size_t)(brow + r0s) * K_DIM + g0 * 16;
    const int8_t* gA1 = A + (size_t)(brow + r1s) * K_DIM + g1 * 16;
    const int8_t* gB0 = B + (size_t)(bcol + r0s) * K_DIM + g0 * 16;
    const int8_t* gB1 = B + (size_t)(bcol + r1s) * K_DIM + g1 * 16;
    const int segb0 = wave * 1024;            // wave-uniform LDS base (HW adds lane*16)
    const int segb1 = segb0 + 8192;

    // ---- compute-side swizzled LDS offsets ----
    const int gsz  = ls ^ ((l15 >> 1) & 3);
    const int offA = (wm * 128 + l15) * BK + gsz * 16;   // + mi*1024 + buf*16384
    const int offB = (wn * 64  + l15) * BK + gsz * 16;   // + ni*1024 + buf*16384

    int32x4 acc[8][4];
#pragma unroll
    for (int i = 0; i < 8; ++i)
#pragma unroll
        for (int j = 0; j < 4; ++j) acc[i][j] = (int32x4){0, 0, 0, 0};

    // ---- prologue: stage tiles 0,1,2 (order per tile: A0,A1,B0,B1) ----
#pragma unroll
    for (int tt = 0; tt < 3; ++tt) {
        GLL(gA0 + tt * BK, lds + tt * 16384 + segb0);
        GLL(gA1 + tt * BK, lds + tt * 16384 + segb1);
        GLL(gB0 + tt * BK, lds + 65536 + tt * 16384 + segb0);
        GLL(gB1 + tt * BK, lds + 65536 + tt * 16384 + segb1);
    }
    asm volatile("s_waitcnt vmcnt(8)" ::: "memory");   // tile 0 landed
    __builtin_amdgcn_s_barrier();

    for (int t = 0; t < NT; ++t) {
        const int8_t* Ab = lds + (t & 3) * 16384;
        const int8_t* Bb = lds + 65536 + (t & 3) * 16384;
        int8_t* dA = lds + ((t + 3) & 3) * 16384;
        int8_t* dB = lds + 65536 + ((t + 3) & 3) * 16384;
        const bool pf = (t + 3 < NT);
        const int kk = (t + 3) * BK;

        int32x4 af[4], bf[4];

        // ================= phase 0 =================
        if (pf) {
            GLL(gA0 + kk, dA + segb0);
            GLL(gA1 + kk, dA + segb1);
        }
#pragma unroll
        for (int mi = 0; mi < 4; ++mi)
            af[mi] = *(const int32x4*)(Ab + offA + mi * 1024);
#pragma unroll
        for (int ni = 0; ni < 4; ++ni)
            bf[ni] = *(const int32x4*)(Bb + offB + ni * 1024);
        __builtin_amdgcn_s_barrier();
        asm volatile("s_waitcnt lgkmcnt(0)" ::: "memory");
        __builtin_amdgcn_sched_barrier(0);
        __builtin_amdgcn_s_setprio(1);
#pragma unroll
        for (int mi = 0; mi < 4; ++mi)
#pragma unroll
            for (int ni = 0; ni < 4; ++ni)
                acc[mi][ni] = MFMA_I8(af[mi], bf[ni], acc[mi][ni]);
        __builtin_amdgcn_s_setprio(0);
        __builtin_amdgcn_s_barrier();

        // ================= phase 1 =================
        if (pf) {
            GLL(gB0 + kk, dB + segb0);
            GLL(gB1 + kk, dB + segb1);
        }
#pragma unroll
        for (int mi = 0; mi < 4; ++mi)
            af[mi] = *(const int32x4*)(Ab + offA + (mi + 4) * 1024);
        __builtin_amdgcn_s_barrier();
        asm volatile("s_waitcnt lgkmcnt(0)" ::: "memory");
        __builtin_amdgcn_sched_barrier(0);
        __builtin_amdgcn_s_setprio(1);
#pragma unroll
        for (int mi = 0; mi < 4; ++mi)
#pragma unroll
            for (int ni = 0; ni < 4; ++ni)
                acc[mi + 4][ni] = MFMA_I8(af[mi], bf[ni], acc[mi + 4][ni]);
        __builtin_amdgcn_s_setprio(0);
        if (t <= NT - 4)      asm volatile("s_waitcnt vmcnt(8)" ::: "memory");
        else if (t == NT - 3) asm volatile("s_waitcnt vmcnt(4)" ::: "memory");
        else                  asm volatile("s_waitcnt vmcnt(0)" ::: "memory");
        __builtin_amdgcn_sched_barrier(0);
        __builtin_amdgcn_s_barrier();
    }

    // ---- epilogue: dequant + fp16-round; C/D: col=lane&15, row=(lane>>4)*4+reg
    const int c0  = lane & 15;
    const int rr0 = (lane >> 4) * 4;
#pragma unroll
    for (int ni = 0; ni < 4; ++ni) {
        const int col = bcol + wn * 64 + ni * 16 + c0;
        const float ws = wsc[col];
#pragma unroll
        for (int mi = 0; mi < 8; ++mi) {
            const int rowb = brow + wm * 128 + mi * 16 + rr0;
#pragma unroll
            for (int r = 0; r < 4; ++r) {
                const int row = rowb + r;
                float o = (float)acc[mi][ni][r] * asc[row] * ws;
                o = (float)(_Float16)o;   // emulate reference's fp16 cast
                C[(size_t)row * N_DIM + col] = o;
            }
        }
    }
}

// ---------------------------------------------------------------------------
extern "C" void kernel_launch(void* const* d_in, const int* in_sizes, int n_in,
                              void* d_out, int out_size, void* d_ws, size_t ws_size,
                              hipStream_t stream) {
    const float* x   = (const float*)d_in[0];   // [M][K], fp16-valued f32
    const int*   w   = (const int*)d_in[1];     // [N][K] int32 (int8-valued)
    const float* wsc = (const float*)d_in[2];   // [N]
    float* out = (float*)d_out;                 // [M][N] (fp16-valued f32)

    const int K = K_DIM;
    const int M = in_sizes[0] / K;              // 8192
    const int N = N_DIM;

    int8_t* q   = (int8_t*)d_ws;                               // M*K  = 32 MB
    int8_t* w8  = (int8_t*)d_ws + (size_t)M * K;               // N*K  = 16 MB
    float*  asc = (float*)((char*)d_ws + (size_t)M * K + (size_t)N * K);

    quant_rows<<<M, 256, 0, stream>>>(x, q, asc);
    pack_w<<<(N * (K / 4)) / 256, 256, 0, stream>>>(w, w8);
    const int grid = (M / BM) * (N / BN);       // 512
    w8a8_gemm256<<<grid, 512, 131072, stream>>>(q, w8, asc, wsc, out, M);
}

// Round 8
// 200.079 us; speedup vs baseline: 1.0019x; 1.0019x over previous
//
#include <hip/hip_runtime.h>
#include <stdint.h>

typedef int int32x4 __attribute__((ext_vector_type(4)));

constexpr int K_DIM = 4096;   // D_IN
constexpr int N_DIM = 4096;   // D_OUT
constexpr float QMAXF = 127.0f;

// ---------------------------------------------------------------------------
// Kernel 1: per-token dynamic absmax quantization
// ---------------------------------------------------------------------------
__global__ __launch_bounds__(256) void quant_rows(const float* __restrict__ x,
                                                  int8_t* __restrict__ q,
                                                  float* __restrict__ scales) {
    const int row = blockIdx.x;
    const int tid = threadIdx.x;
    const size_t base = (size_t)row * K_DIM;

    const float4* xv = reinterpret_cast<const float4*>(x + base);
    float4 v[4];
#pragma unroll
    for (int i = 0; i < 4; ++i) v[i] = xv[tid + 256 * i];

    float m = 0.0f;
#pragma unroll
    for (int i = 0; i < 4; ++i)
        m = fmaxf(m, fmaxf(fmaxf(fabsf(v[i].x), fabsf(v[i].y)),
                           fmaxf(fabsf(v[i].z), fabsf(v[i].w))));
#pragma unroll
    for (int off = 32; off > 0; off >>= 1) m = fmaxf(m, __shfl_xor(m, off));

    __shared__ float wmax[4];
    if ((tid & 63) == 0) wmax[tid >> 6] = m;
    __syncthreads();
    const float am = fmaxf(fmaxf(wmax[0], wmax[1]), fmaxf(wmax[2], wmax[3]));
    const float scale = fmaxf(am * (1.0f / 127.0f), 1e-8f);
    if (tid == 0) scales[row] = scale;
    const float inv = 1.0f / scale;

    int* qw = reinterpret_cast<int*>(q + base);
#pragma unroll
    for (int i = 0; i < 4; ++i) {
        float f0 = fminf(QMAXF, fmaxf(-QMAXF, rintf(v[i].x * inv)));
        float f1 = fminf(QMAXF, fmaxf(-QMAXF, rintf(v[i].y * inv)));
        float f2 = fminf(QMAXF, fmaxf(-QMAXF, rintf(v[i].z * inv)));
        float f3 = fminf(QMAXF, fmaxf(-QMAXF, rintf(v[i].w * inv)));
        int b0 = ((int)f0) & 255, b1 = ((int)f1) & 255;
        int b2 = ((int)f2) & 255, b3 = ((int)f3) & 255;
        qw[tid + 256 * i] = b0 | (b1 << 8) | (b2 << 16) | (b3 << 24);
    }
}

// ---------------------------------------------------------------------------
// Kernel 2: pack int32 weight buffer -> int8
// ---------------------------------------------------------------------------
__global__ __launch_bounds__(256) void pack_w(const int* __restrict__ w,
                                              int8_t* __restrict__ w8) {
    const int idx = blockIdx.x * 256 + threadIdx.x;
    const int4 v = reinterpret_cast<const int4*>(w)[idx];
    int packed = (v.x & 255) | ((v.y & 255) << 8) | ((v.z & 255) << 16) | ((v.w & 255) << 24);
    reinterpret_cast<int*>(w8)[idx] = packed;
}

// ---------------------------------------------------------------------------
// Kernel 3: int8 GEMM — TWO INDEPENDENT BLOCKS PER CU.
// Block: 256 threads = 4 waves (2Mx2N), block tile 256x128, wave tile 128x64.
// BK=64, ring-3 LDS (A 3x16KB + B 3x8KB = 72KB) -> 2 blocks/CU resident.
// While one block's waves drain their LDS read burst / sit at the barrier,
// the other block's waves feed the matrix pipe on the same SIMDs -> the
// LDS/MFMA alternation that capped rounds 2-7 at 34-38% now overlaps
// ACROSS blocks instead of serializing within one barrier domain.
//
// Staging: 6 GLL/thread/tile (A: 4 chunks of 64 rows, B: 2 chunks), ring
// distance 2. End-of-tile gate vmcnt(6) leaves tile t+2's 6 loads in
// flight (never drains until the tail). WAR: GLL(t+2) -> slot (t+2)%3 =
// (t-1)%3, whose reads drained (lgkmcnt(0)) before the end-of-(t-1)
// barrier. Visibility: vmcnt gate at end of t-1 + barrier.
// LDS swizzle (verified 0 conflicts, rounds 2-7): seg s -> row s>>2,
// slot s&3, stored granule (s&3)^((row>>1)&3); read slot ls^((l15>>1)&3).
// ---------------------------------------------------------------------------
constexpr int BM = 256, BN = 128, BK = 64;
constexpr int NT = K_DIM / BK;     // 64 K-tiles
constexpr int A_RING = 16384;      // 256*64 per slot
constexpr int B_RING = 8192;       // 128*64 per slot
constexpr int B_BASE = 3 * A_RING; // 49152

#define GLL(src, dst)                                                          \
    __builtin_amdgcn_global_load_lds(                                          \
        (const __attribute__((address_space(1))) unsigned int*)(src),          \
        (__attribute__((address_space(3))) unsigned int*)(dst), 16, 0, 0)

#define MFMA_I8(a, b, c) __builtin_amdgcn_mfma_i32_16x16x64_i8((a), (b), (c), 0, 0, 0)

__global__ __launch_bounds__(256, 2) void w8a8_gemm(
        const int8_t* __restrict__ A, const int8_t* __restrict__ B,
        const float* __restrict__ asc, const float* __restrict__ wsc,
        float* __restrict__ C, int M) {
    extern __shared__ int8_t lds[];   // 72 KB

    const int tid  = threadIdx.x;
    const int lane = tid & 63;
    const int wave = tid >> 6;

    // XCD-aware bijective swizzle (nwg = 1024, divisible by 8)
    const int nwg = gridDim.x;
    const int bid = blockIdx.x;
    const int swz = (bid & 7) * (nwg >> 3) + (bid >> 3);
    const int brow = (swz >> 5) * BM;          // 32 col-blocks per row
    const int bcol = (swz & 31) * BN;

    const int wm = wave >> 1;                  // 0..1 (128-row half)
    const int wn = wave & 1;                   // 0..1 (64-col half)
    const int l15 = lane & 15;
    const int ls  = lane >> 4;

    // ---- staging (per-lane pre-swizzled GLOBAL source, linear LDS dest) ----
    const int rowst = tid >> 2;                         // 0..63 within chunk
    const int g     = (tid & 3) ^ ((tid >> 3) & 3);     // swizzled granule
    const int8_t* gA = A + (size_t)(brow + rowst) * K_DIM + g * 16;
    const int8_t* gB = B + (size_t)(bcol + rowst) * K_DIM + g * 16;
    const size_t chunk_g = (size_t)64 * K_DIM;
    const int wbase = wave * 1024;                      // wave-uniform LDS base

    // ---- compute-side swizzled LDS offsets ----
    const int gsz  = ls ^ ((l15 >> 1) & 3);
    const int offA = (wm * 128 + l15) * BK + gsz * 16;  // + mi*1024 + slot*A_RING
    const int offB = (wn * 64  + l15) * BK + gsz * 16;  // + ni*1024 + slot*B_RING

    int32x4 acc[8][4];
#pragma unroll
    for (int i = 0; i < 8; ++i)
#pragma unroll
        for (int j = 0; j < 4; ++j) acc[i][j] = (int32x4){0, 0, 0, 0};

    // ---- prologue: stage tiles 0 and 1 ----
#pragma unroll
    for (int tt = 0; tt < 2; ++tt) {
#pragma unroll
        for (int c = 0; c < 4; ++c)
            GLL(gA + tt * BK + c * chunk_g, lds + tt * A_RING + c * 4096 + wbase);
#pragma unroll
        for (int c = 0; c < 2; ++c)
            GLL(gB + tt * BK + c * chunk_g, lds + B_BASE + tt * B_RING + c * 4096 + wbase);
    }
    asm volatile("s_waitcnt vmcnt(6)" ::: "memory");   // tile 0 landed
    __builtin_amdgcn_s_barrier();

    for (int t = 0; t < NT; ++t) {
        const int cs = t % 3;
        const int8_t* Ab = lds + cs * A_RING;
        const int8_t* Bb = lds + B_BASE + cs * B_RING;

        // stage tile t+2 into ring slot (t+2)%3
        if (t < NT - 2) {
            const int ps = (t + 2) % 3;
            const int kk = (t + 2) * BK;
#pragma unroll
            for (int c = 0; c < 4; ++c)
                GLL(gA + kk + c * chunk_g, lds + ps * A_RING + c * 4096 + wbase);
#pragma unroll
            for (int c = 0; c < 2; ++c)
                GLL(gB + kk + c * chunk_g, lds + B_BASE + ps * B_RING + c * 4096 + wbase);
        }

        int32x4 af[8], bf[4];
#pragma unroll
        for (int mi = 0; mi < 8; ++mi)
            af[mi] = *(const int32x4*)(Ab + offA + mi * 1024);
#pragma unroll
        for (int ni = 0; ni < 4; ++ni)
            bf[ni] = *(const int32x4*)(Bb + offB + ni * 1024);

        asm volatile("s_waitcnt lgkmcnt(0)" ::: "memory");
        __builtin_amdgcn_sched_barrier(0);
        __builtin_amdgcn_s_setprio(1);
#pragma unroll
        for (int mi = 0; mi < 8; ++mi)
#pragma unroll
            for (int ni = 0; ni < 4; ++ni)
                acc[mi][ni] = MFMA_I8(af[mi], bf[ni], acc[mi][ni]);
        __builtin_amdgcn_s_setprio(0);

        if (t < NT - 2)       asm volatile("s_waitcnt vmcnt(6)" ::: "memory");
        else if (t == NT - 2) asm volatile("s_waitcnt vmcnt(0)" ::: "memory");
        __builtin_amdgcn_sched_barrier(0);
        __builtin_amdgcn_s_barrier();
    }

    // ---- epilogue: dequant + fp16-round; C/D: col=lane&15, row=(lane>>4)*4+reg
    const int c0  = lane & 15;
    const int rr0 = (lane >> 4) * 4;
#pragma unroll
    for (int ni = 0; ni < 4; ++ni) {
        const int col = bcol + wn * 64 + ni * 16 + c0;
        const float ws = wsc[col];
#pragma unroll
        for (int mi = 0; mi < 8; ++mi) {
            const int rowb = brow + wm * 128 + mi * 16 + rr0;
#pragma unroll
            for (int r = 0; r < 4; ++r) {
                const int row = rowb + r;
                float o = (float)acc[mi][ni][r] * asc[row] * ws;
                o = (float)(_Float16)o;   // emulate reference's fp16 cast
                C[(size_t)row * N_DIM + col] = o;
            }
        }
    }
}

// ---------------------------------------------------------------------------
extern "C" void kernel_launch(void* const* d_in, const int* in_sizes, int n_in,
                              void* d_out, int out_size, void* d_ws, size_t ws_size,
                              hipStream_t stream) {
    const float* x   = (const float*)d_in[0];   // [M][K], fp16-valued f32
    const int*   w   = (const int*)d_in[1];     // [N][K] int32 (int8-valued)
    const float* wsc = (const float*)d_in[2];   // [N]
    float* out = (float*)d_out;                 // [M][N] (fp16-valued f32)

    const int K = K_DIM;
    const int M = in_sizes[0] / K;              // 8192
    const int N = N_DIM;

    int8_t* q   = (int8_t*)d_ws;                               // M*K  = 32 MB
    int8_t* w8  = (int8_t*)d_ws + (size_t)M * K;               // N*K  = 16 MB
    float*  asc = (float*)((char*)d_ws + (size_t)M * K + (size_t)N * K);

    quant_rows<<<M, 256, 0, stream>>>(x, q, asc);
    pack_w<<<(N * (K / 4)) / 256, 256, 0, stream>>>(w, w8);
    const int grid = (M / BM) * (N / BN);       // 32 x 32 = 1024
    w8a8_gemm<<<grid, 256, 73728, stream>>>(q, w8, asc, wsc, out, M);
}

// Round 9
// 197.283 us; speedup vs baseline: 1.0161x; 1.0142x over previous
//
#include <hip/hip_runtime.h>
#include <stdint.h>

typedef int int32x4  __attribute__((ext_vector_type(4)));
typedef int int32x16 __attribute__((ext_vector_type(16)));

constexpr int K_DIM = 4096;   // D_IN
constexpr int N_DIM = 4096;   // D_OUT
constexpr float QMAXF = 127.0f;

// ---------------------------------------------------------------------------
// Kernel 1: per-token dynamic absmax quantization
// ---------------------------------------------------------------------------
__global__ __launch_bounds__(256) void quant_rows(const float* __restrict__ x,
                                                  int8_t* __restrict__ q,
                                                  float* __restrict__ scales) {
    const int row = blockIdx.x;
    const int tid = threadIdx.x;
    const size_t base = (size_t)row * K_DIM;

    const float4* xv = reinterpret_cast<const float4*>(x + base);
    float4 v[4];
#pragma unroll
    for (int i = 0; i < 4; ++i) v[i] = xv[tid + 256 * i];

    float m = 0.0f;
#pragma unroll
    for (int i = 0; i < 4; ++i)
        m = fmaxf(m, fmaxf(fmaxf(fabsf(v[i].x), fabsf(v[i].y)),
                           fmaxf(fabsf(v[i].z), fabsf(v[i].w))));
#pragma unroll
    for (int off = 32; off > 0; off >>= 1) m = fmaxf(m, __shfl_xor(m, off));

    __shared__ float wmax[4];
    if ((tid & 63) == 0) wmax[tid >> 6] = m;
    __syncthreads();
    const float am = fmaxf(fmaxf(wmax[0], wmax[1]), fmaxf(wmax[2], wmax[3]));
    const float scale = fmaxf(am * (1.0f / 127.0f), 1e-8f);
    if (tid == 0) scales[row] = scale;
    const float inv = 1.0f / scale;

    int* qw = reinterpret_cast<int*>(q + base);
#pragma unroll
    for (int i = 0; i < 4; ++i) {
        float f0 = fminf(QMAXF, fmaxf(-QMAXF, rintf(v[i].x * inv)));
        float f1 = fminf(QMAXF, fmaxf(-QMAXF, rintf(v[i].y * inv)));
        float f2 = fminf(QMAXF, fmaxf(-QMAXF, rintf(v[i].z * inv)));
        float f3 = fminf(QMAXF, fmaxf(-QMAXF, rintf(v[i].w * inv)));
        int b0 = ((int)f0) & 255, b1 = ((int)f1) & 255;
        int b2 = ((int)f2) & 255, b3 = ((int)f3) & 255;
        qw[tid + 256 * i] = b0 | (b1 << 8) | (b2 << 16) | (b3 << 24);
    }
}

// ---------------------------------------------------------------------------
// Kernel 2: pack int32 weight buffer -> int8
// ---------------------------------------------------------------------------
__global__ __launch_bounds__(256) void pack_w(const int* __restrict__ w,
                                              int8_t* __restrict__ w8) {
    const int idx = blockIdx.x * 256 + threadIdx.x;
    const int4 v = reinterpret_cast<const int4*>(w)[idx];
    int packed = (v.x & 255) | ((v.y & 255) << 8) | ((v.z & 255) << 16) | ((v.w & 255) << 24);
    reinterpret_cast<int*>(w8)[idx] = packed;
}

// ---------------------------------------------------------------------------
// Kernel 3: int8 GEMM with mfma_i32_32x32x32_i8 (2x work/instr vs 16x16x64;
// 4404 vs 3944 TOPS ubench). r6 skeleton: 256x256 tile, BK=128, 8 waves
// (2Mx4N of 128x64), 2-deep LDS dbuf (128 KB), 2 barriers + counted vmcnt
// per tile (never drains in steady state), barrier-free interior of 8
// sub-phases {<=4 ds_read_b128 | 4 dependent-ks MFMA}.
//
// GLL ledger (verified r6): A(t+1)x4 at tile top after WAR barrier ->
// vmcnt(4) leaves A(t+1) in flight, guarantees A(t)+B(t) landed; B(t+1)x4
// at sub-phase (2,1). Tail t=NT-1: vmcnt(0).
//
// Fragments (32x32x32 i8): A lane l: row l&31, k-bytes [16*(l>>5)+32*ks);
// B (from B^T LDS): col l&31, same k mapping. C/D: col=lane&31,
// row=(reg&3)+8*(reg>>2)+4*(lane>>5), reg 0..15 [m74/m101].
//
// LDS swizzle (8-slot, verified 0 conflicts r5/r6): row r slot s holds
// global granule s^(r&7); staged via pre-swizzled global source (linear
// LDS dest); read at slot (2*ks+lh)^(l31&7).
// ---------------------------------------------------------------------------
constexpr int BM = 256, BN = 256, BKB = 128;
constexpr int NT = K_DIM / BKB;    // 32 K-tiles

#define GLL(src, dst)                                                          \
    __builtin_amdgcn_global_load_lds(                                          \
        (const __attribute__((address_space(1))) unsigned int*)(src),          \
        (__attribute__((address_space(3))) unsigned int*)(dst), 16, 0, 0)

#define MFMA32(a, b, c) __builtin_amdgcn_mfma_i32_32x32x32_i8((a), (b), (c), 0, 0, 0)

// 4 dependent-ks MFMAs on one accumulator quadrant, setprio-wrapped
#define MFMA4(ACC, AF, BF)                                                     \
    {                                                                          \
        __builtin_amdgcn_s_setprio(1);                                         \
        ACC = MFMA32(AF[0], BF[0], ACC);                                       \
        ACC = MFMA32(AF[1], BF[1], ACC);                                       \
        ACC = MFMA32(AF[2], BF[2], ACC);                                       \
        ACC = MFMA32(AF[3], BF[3], ACC);                                       \
        __builtin_amdgcn_s_setprio(0);                                         \
    }

__global__ __launch_bounds__(512, 2) void w8a8_gemm256(
        const int8_t* __restrict__ A, const int8_t* __restrict__ B,
        const float* __restrict__ asc, const float* __restrict__ wsc,
        float* __restrict__ C, int M) {
    extern __shared__ int8_t lds[];   // 128 KB: A dbuf @0, B dbuf @65536

    const int tid  = threadIdx.x;
    const int lane = tid & 63;
    const int wave = tid >> 6;

    // XCD-aware bijective swizzle (nwg = 512, divisible by 8)
    const int nwg = gridDim.x;
    const int bid = blockIdx.x;
    const int swz = (bid & 7) * (nwg >> 3) + (bid >> 3);
    const int NB  = N_DIM / BN;               // 16
    const int brow = (swz / NB) * BM;
    const int bcol = (swz % NB) * BN;

    const int wm = wave >> 2;                 // 0..1
    const int wn = wave & 3;                  // 0..3
    const int l31 = lane & 31;
    const int lh  = lane >> 5;                // 0..1

    // ---- staging (per-lane pre-swizzled GLOBAL source, linear LDS dest) ----
    const int rowin = tid >> 3;                         // 0..63 within chunk
    const int gsl   = ((tid & 7) ^ (rowin & 7)) * 16;   // swizzled granule
    const int8_t* gA = A + (size_t)(brow + rowin) * K_DIM + gsl;
    const int8_t* gB = B + (size_t)(bcol + rowin) * K_DIM + gsl;
    const size_t chunk_g = (size_t)64 * K_DIM;
    const int segb = wave * 1024;                       // wave-uniform LDS base

    // ---- compute-side swizzled LDS offsets ----
    const int sb = lh ^ (l31 & 7);                      // slot base (ks=0)
    const int baseA = (wm * 128 + l31) * BKB;           // + mi*4096 + slot*16
    const int baseB = (wn * 64  + l31) * BKB;           // + ni*4096 + slot*16
    // slot(ks) = sb ^ (2*ks)

    int32x16 acc[4][2];
#pragma unroll
    for (int i = 0; i < 4; ++i)
#pragma unroll
        for (int j = 0; j < 2; ++j)
#pragma unroll
            for (int e = 0; e < 16; ++e) acc[i][j][e] = 0;

    // ---- prologue: stage tile 0 fully ----
#pragma unroll
    for (int c = 0; c < 4; ++c) {
        GLL(gA + c * chunk_g, lds + c * 8192 + segb);
        GLL(gB + c * chunk_g, lds + 65536 + c * 8192 + segb);
    }
    asm volatile("s_waitcnt vmcnt(0)" ::: "memory");
    __builtin_amdgcn_s_barrier();

    int32x4 af[2][4], bf[2][4];

    for (int t = 0; t < NT; ++t) {
        const int8_t* Ab = lds + (t & 1) * 32768;
        const int8_t* Bb = lds + 65536 + (t & 1) * 32768;
        int8_t* dA = lds + ((t + 1) & 1) * 32768;
        int8_t* dB = lds + 65536 + ((t + 1) & 1) * 32768;
        const bool pf = (t + 1 < NT);
        const size_t kk = (size_t)(t + 1) * BKB;

        // B1: WAR fence — all waves done reading buf[(t+1)&1]
        __builtin_amdgcn_s_barrier();
        if (pf) {
#pragma unroll
            for (int c = 0; c < 4; ++c)
                GLL(gA + kk + c * chunk_g, dA + c * 8192 + segb);
            asm volatile("s_waitcnt vmcnt(4)" ::: "memory");   // tile t landed
        } else {
            asm volatile("s_waitcnt vmcnt(0)" ::: "memory");
        }
        // B2: staging visibility block-wide
        __builtin_amdgcn_s_barrier();

        // tile-top reads: A[0] and B[0] (4 ds_read_b128 each)
#pragma unroll
        for (int ks = 0; ks < 4; ++ks) {
            af[0][ks] = *(const int32x4*)(Ab + baseA + ((sb ^ (2 * ks)) * 16));
            bf[0][ks] = *(const int32x4*)(Bb + baseB + ((sb ^ (2 * ks)) * 16));
        }

        // ---- 8 sub-phases, barrier-free; compiler inserts minimal lgkm waits
        // ph(0,0): issue B[1]; MFMA m0n0
#pragma unroll
        for (int ks = 0; ks < 4; ++ks)
            bf[1][ks] = *(const int32x4*)(Bb + baseB + 4096 + ((sb ^ (2 * ks)) * 16));
        MFMA4(acc[0][0], af[0], bf[0]);

        // ph(0,1): issue A[1]; MFMA m0n1
#pragma unroll
        for (int ks = 0; ks < 4; ++ks)
            af[1][ks] = *(const int32x4*)(Ab + baseA + 4096 + ((sb ^ (2 * ks)) * 16));
        MFMA4(acc[0][1], af[0], bf[1]);

        // ph(1,0): issue A[2] -> af[0]; MFMA m1n0
#pragma unroll
        for (int ks = 0; ks < 4; ++ks)
            af[0][ks] = *(const int32x4*)(Ab + baseA + 8192 + ((sb ^ (2 * ks)) * 16));
        MFMA4(acc[1][0], af[1], bf[0]);

        // ph(1,1): MFMA m1n1
        MFMA4(acc[1][1], af[1], bf[1]);

        // ph(2,0): issue A[3] -> af[1]; MFMA m2n0
#pragma unroll
        for (int ks = 0; ks < 4; ++ks)
            af[1][ks] = *(const int32x4*)(Ab + baseA + 12288 + ((sb ^ (2 * ks)) * 16));
        MFMA4(acc[2][0], af[0], bf[0]);

        // ph(2,1): GLL B(t+1); MFMA m2n1
        if (pf) {
#pragma unroll
            for (int c = 0; c < 4; ++c)
                GLL(gB + kk + c * chunk_g, dB + c * 8192 + segb);
        }
        MFMA4(acc[2][1], af[0], bf[1]);

        // ph(3,0) / ph(3,1)
        MFMA4(acc[3][0], af[1], bf[0]);
        MFMA4(acc[3][1], af[1], bf[1]);
    }

    // ---- epilogue: dequant + fp16-round
    // C/D 32x32: col = lane&31, row = (reg&3) + 8*(reg>>2) + 4*(lane>>5)
#pragma unroll
    for (int ni = 0; ni < 2; ++ni) {
        const int col = bcol + wn * 64 + ni * 32 + l31;
        const float ws = wsc[col];
#pragma unroll
        for (int mi = 0; mi < 4; ++mi) {
            const int rowb = brow + wm * 128 + mi * 32 + 4 * lh;
#pragma unroll
            for (int r = 0; r < 16; ++r) {
                const int row = rowb + (r & 3) + 8 * (r >> 2);
                float o = (float)acc[mi][ni][r] * asc[row] * ws;
                o = (float)(_Float16)o;   // emulate reference's fp16 cast
                C[(size_t)row * N_DIM + col] = o;
            }
        }
    }
}

// ---------------------------------------------------------------------------
extern "C" void kernel_launch(void* const* d_in, const int* in_sizes, int n_in,
                              void* d_out, int out_size, void* d_ws, size_t ws_size,
                              hipStream_t stream) {
    const float* x   = (const float*)d_in[0];   // [M][K], fp16-valued f32
    const int*   w   = (const int*)d_in[1];     // [N][K] int32 (int8-valued)
    const float* wsc = (const float*)d_in[2];   // [N]
    float* out = (float*)d_out;                 // [M][N] (fp16-valued f32)

    const int K = K_DIM;
    const int M = in_sizes[0] / K;              // 8192
    const int N = N_DIM;

    int8_t* q   = (int8_t*)d_ws;                               // M*K  = 32 MB
    int8_t* w8  = (int8_t*)d_ws + (size_t)M * K;               // N*K  = 16 MB
    float*  asc = (float*)((char*)d_ws + (size_t)M * K + (size_t)N * K);

    quant_rows<<<M, 256, 0, stream>>>(x, q, asc);
    pack_w<<<(N * (K / 4)) / 256, 256, 0, stream>>>(w, w8);
    const int grid = (M / BM) * (N / BN);       // 512
    w8a8_gemm256<<<grid, 512, 131072, stream>>>(q, w8, asc, wsc, out, M);
}

// Round 10
// 194.200 us; speedup vs baseline: 1.0322x; 1.0159x over previous
//
#include <hip/hip_runtime.h>
#include <stdint.h>

typedef int int32x4  __attribute__((ext_vector_type(4)));
typedef int int32x16 __attribute__((ext_vector_type(16)));

constexpr int K_DIM = 4096;   // D_IN
constexpr int N_DIM = 4096;   // D_OUT
constexpr float QMAXF = 127.0f;

// ---------------------------------------------------------------------------
// Kernel 1: per-token dynamic absmax quantization
// ---------------------------------------------------------------------------
__global__ __launch_bounds__(256) void quant_rows(const float* __restrict__ x,
                                                  int8_t* __restrict__ q,
                                                  float* __restrict__ scales) {
    const int row = blockIdx.x;
    const int tid = threadIdx.x;
    const size_t base = (size_t)row * K_DIM;

    const float4* xv = reinterpret_cast<const float4*>(x + base);
    float4 v[4];
#pragma unroll
    for (int i = 0; i < 4; ++i) v[i] = xv[tid + 256 * i];

    float m = 0.0f;
#pragma unroll
    for (int i = 0; i < 4; ++i)
        m = fmaxf(m, fmaxf(fmaxf(fabsf(v[i].x), fabsf(v[i].y)),
                           fmaxf(fabsf(v[i].z), fabsf(v[i].w))));
#pragma unroll
    for (int off = 32; off > 0; off >>= 1) m = fmaxf(m, __shfl_xor(m, off));

    __shared__ float wmax[4];
    if ((tid & 63) == 0) wmax[tid >> 6] = m;
    __syncthreads();
    const float am = fmaxf(fmaxf(wmax[0], wmax[1]), fmaxf(wmax[2], wmax[3]));
    const float scale = fmaxf(am * (1.0f / 127.0f), 1e-8f);
    if (tid == 0) scales[row] = scale;
    const float inv = 1.0f / scale;

    int* qw = reinterpret_cast<int*>(q + base);
#pragma unroll
    for (int i = 0; i < 4; ++i) {
        float f0 = fminf(QMAXF, fmaxf(-QMAXF, rintf(v[i].x * inv)));
        float f1 = fminf(QMAXF, fmaxf(-QMAXF, rintf(v[i].y * inv)));
        float f2 = fminf(QMAXF, fmaxf(-QMAXF, rintf(v[i].z * inv)));
        float f3 = fminf(QMAXF, fmaxf(-QMAXF, rintf(v[i].w * inv)));
        int b0 = ((int)f0) & 255, b1 = ((int)f1) & 255;
        int b2 = ((int)f2) & 255, b3 = ((int)f3) & 255;
        qw[tid + 256 * i] = b0 | (b1 << 8) | (b2 << 16) | (b3 << 24);
    }
}

// ---------------------------------------------------------------------------
// Kernel 2: pack int32 weight buffer -> int8
// ---------------------------------------------------------------------------
__global__ __launch_bounds__(256) void pack_w(const int* __restrict__ w,
                                              int8_t* __restrict__ w8) {
    const int idx = blockIdx.x * 256 + threadIdx.x;
    const int4 v = reinterpret_cast<const int4*>(w)[idx];
    int packed = (v.x & 255) | ((v.y & 255) << 8) | ((v.z & 255) << 16) | ((v.w & 255) << 24);
    reinterpret_cast<int*>(w8)[idx] = packed;
}

// ---------------------------------------------------------------------------
// Kernel 3: int8 GEMM, mfma_i32_32x32x32_i8, CONFLICT-FREE sub-tiled LDS.
// r6 skeleton: 256x256 tile, BKB=128, 8 waves (2Mx4N of 128x64), dbuf-2
// (128 KB), 2 barriers + counted vmcnt per tile, barrier-free interior.
//
// LDS layout (the round-10 fix): each BKB=128 tile stored as TWO sub-tiles
// [sub(2)][row(256)][64B] -> row stride 64 B, so row bit 0 lands in bank
// bit 6. Verified rule (r2-r8 = 0 conflicts, r9 @128B stride = 1.26e7):
// slot-XOR + row-parity spreads a 16-lane group to 2 lanes/bank = free.
//   store: (sub,row,slot) holds global kbyte sub*64 + (slot^((row>>1)&3))*16
//   staged via pre-swizzled GLOBAL source, linear LDS dest (rule 21):
//     thread(c,wave,lane): row = (c&1)*128 + wave*16 + (lane>>2),
//     slot = lane&3, g = (lane&3)^((lane>>3)&3)  [independent of c,wave]
//   read:  ks in 0..3 -> sub = ks>>1, gran = lh+2*(ks&1),
//          slot = gran ^ ((l31>>1)&3)
//
// GLL ledger (verified r6/r9): A(t+1)x4 at tile top after WAR barrier ->
// vmcnt(4) guarantees tile t landed, leaves A(t+1) in flight; B(t+1)x4 at
// sub-phase (2,1). Tail t=NT-1: vmcnt(0).
// C/D 32x32 (verified r9): col=lane&31, row=(reg&3)+8*(reg>>2)+4*(lane>>5).
// ---------------------------------------------------------------------------
constexpr int BM = 256, BN = 256, BKB = 128;
constexpr int NT = K_DIM / BKB;    // 32 K-tiles

#define GLL(src, dst)                                                          \
    __builtin_amdgcn_global_load_lds(                                          \
        (const __attribute__((address_space(1))) unsigned int*)(src),          \
        (__attribute__((address_space(3))) unsigned int*)(dst), 16, 0, 0)

#define MFMA32(a, b, c) __builtin_amdgcn_mfma_i32_32x32x32_i8((a), (b), (c), 0, 0, 0)

// 4 dependent-ks MFMAs on one accumulator quadrant, setprio-wrapped
#define MFMA4(ACC, AF, BF)                                                     \
    {                                                                          \
        __builtin_amdgcn_s_setprio(1);                                         \
        ACC = MFMA32(AF[0], BF[0], ACC);                                       \
        ACC = MFMA32(AF[1], BF[1], ACC);                                       \
        ACC = MFMA32(AF[2], BF[2], ACC);                                       \
        ACC = MFMA32(AF[3], BF[3], ACC);                                       \
        __builtin_amdgcn_s_setprio(0);                                         \
    }

// load one 4-ks fragment set from sub-tiled LDS (P = tile base + row base)
#define LDFRAG(DST, P, OFF)                                                    \
    DST[0] = *(const int32x4*)((P) + (OFF) + sl0b);                            \
    DST[1] = *(const int32x4*)((P) + (OFF) + (sl0b ^ 32));                     \
    DST[2] = *(const int32x4*)((P) + (OFF) + 16384 + sl0b);                    \
    DST[3] = *(const int32x4*)((P) + (OFF) + 16384 + (sl0b ^ 32));

__global__ __launch_bounds__(512, 2) void w8a8_gemm256(
        const int8_t* __restrict__ A, const int8_t* __restrict__ B,
        const float* __restrict__ asc, const float* __restrict__ wsc,
        float* __restrict__ C, int M) {
    extern __shared__ int8_t lds[];   // 128 KB: A dbuf @0, B dbuf @65536

    const int tid  = threadIdx.x;
    const int lane = tid & 63;
    const int wave = tid >> 6;

    // XCD-aware bijective swizzle (nwg = 512, divisible by 8)
    const int nwg = gridDim.x;
    const int bid = blockIdx.x;
    const int swz = (bid & 7) * (nwg >> 3) + (bid >> 3);
    const int NB  = N_DIM / BN;               // 16
    const int brow = (swz / NB) * BM;
    const int bcol = (swz % NB) * BN;

    const int wm = wave >> 2;                 // 0..1
    const int wn = wave & 3;                  // 0..3
    const int l31 = lane & 31;
    const int lh  = lane >> 5;                // 0..1

    // ---- staging (per-lane pre-swizzled GLOBAL source, linear LDS dest) ----
    const int rowch = wave * 16 + (lane >> 2);            // 0..127
    const int g     = ((lane & 3) ^ ((lane >> 3) & 3)) * 16;
    const int8_t* gA = A + (size_t)(brow + rowch) * K_DIM + g;
    const int8_t* gB = B + (size_t)(bcol + rowch) * K_DIM + g;
    // chunk c: global += (c&1)*128 rows, (c>>1)*64 kbytes
    const int segb = wave * 1024;                         // wave-uniform LDS base

    // ---- compute-side swizzled LDS offsets ----
    const int q4   = (l31 >> 1) & 3;
    const int sl0b = (lh ^ q4) * 16;                      // slot bytes for ks=0
    const int baseA = (wm * 128 + l31) * 64;              // + mi*2048 (+16384 sub1)
    const int baseB = (wn * 64  + l31) * 64;              // + ni*2048 (+16384 sub1)

    int32x16 acc[4][2];
#pragma unroll
    for (int i = 0; i < 4; ++i)
#pragma unroll
        for (int j = 0; j < 2; ++j)
#pragma unroll
            for (int e = 0; e < 16; ++e) acc[i][j][e] = 0;

    // ---- prologue: stage tile 0 fully ----
#pragma unroll
    for (int c = 0; c < 4; ++c) {
        const size_t cg = (size_t)(c & 1) * 128 * K_DIM + (c >> 1) * 64;
        GLL(gA + cg, lds + c * 8192 + segb);
        GLL(gB + cg, lds + 65536 + c * 8192 + segb);
    }
    asm volatile("s_waitcnt vmcnt(0)" ::: "memory");
    __builtin_amdgcn_s_barrier();

    int32x4 af[2][4], bf[2][4];

    for (int t = 0; t < NT; ++t) {
        const int8_t* Ab = lds + (t & 1) * 32768 + baseA;
        const int8_t* Bb = lds + 65536 + (t & 1) * 32768 + baseB;
        int8_t* dA = lds + ((t + 1) & 1) * 32768;
        int8_t* dB = lds + 65536 + ((t + 1) & 1) * 32768;
        const bool pf = (t + 1 < NT);
        const size_t kk = (size_t)(t + 1) * BKB;

        // B1: WAR fence — all waves done reading buf[(t+1)&1]
        __builtin_amdgcn_s_barrier();
        if (pf) {
#pragma unroll
            for (int c = 0; c < 4; ++c) {
                const size_t cg = (size_t)(c & 1) * 128 * K_DIM + (c >> 1) * 64;
                GLL(gA + kk + cg, dA + c * 8192 + segb);
            }
            asm volatile("s_waitcnt vmcnt(4)" ::: "memory");   // tile t landed
        } else {
            asm volatile("s_waitcnt vmcnt(0)" ::: "memory");
        }
        // B2: staging visibility block-wide
        __builtin_amdgcn_s_barrier();

        // tile-top reads: A[0] and B[0]
        LDFRAG(af[0], Ab, 0);
        LDFRAG(bf[0], Bb, 0);

        // ---- 8 sub-phases, barrier-free; compiler inserts minimal lgkm waits
        // ph(0,0): issue B[1]; MFMA m0n0
        LDFRAG(bf[1], Bb, 2048);
        MFMA4(acc[0][0], af[0], bf[0]);

        // ph(0,1): issue A[1]; MFMA m0n1
        LDFRAG(af[1], Ab, 2048);
        MFMA4(acc[0][1], af[0], bf[1]);

        // ph(1,0): issue A[2] -> af[0]; MFMA m1n0
        LDFRAG(af[0], Ab, 4096);
        MFMA4(acc[1][0], af[1], bf[0]);

        // ph(1,1): MFMA m1n1
        MFMA4(acc[1][1], af[1], bf[1]);

        // ph(2,0): issue A[3] -> af[1]; MFMA m2n0
        LDFRAG(af[1], Ab, 6144);
        MFMA4(acc[2][0], af[0], bf[0]);

        // ph(2,1): GLL B(t+1); MFMA m2n1
        if (pf) {
#pragma unroll
            for (int c = 0; c < 4; ++c) {
                const size_t cg = (size_t)(c & 1) * 128 * K_DIM + (c >> 1) * 64;
                GLL(gB + kk + cg, dB + c * 8192 + segb);
            }
        }
        MFMA4(acc[2][1], af[0], bf[1]);

        // ph(3,0) / ph(3,1)
        MFMA4(acc[3][0], af[1], bf[0]);
        MFMA4(acc[3][1], af[1], bf[1]);
    }

    // ---- epilogue: dequant + fp16-round
    // C/D 32x32: col = lane&31, row = (reg&3) + 8*(reg>>2) + 4*(lane>>5)
#pragma unroll
    for (int ni = 0; ni < 2; ++ni) {
        const int col = bcol + wn * 64 + ni * 32 + l31;
        const float ws = wsc[col];
#pragma unroll
        for (int mi = 0; mi < 4; ++mi) {
            const int rowb = brow + wm * 128 + mi * 32 + 4 * lh;
#pragma unroll
            for (int r = 0; r < 16; ++r) {
                const int row = rowb + (r & 3) + 8 * (r >> 2);
                float o = (float)acc[mi][ni][r] * asc[row] * ws;
                o = (float)(_Float16)o;   // emulate reference's fp16 cast
                C[(size_t)row * N_DIM + col] = o;
            }
        }
    }
}

// ---------------------------------------------------------------------------
extern "C" void kernel_launch(void* const* d_in, const int* in_sizes, int n_in,
                              void* d_out, int out_size, void* d_ws, size_t ws_size,
                              hipStream_t stream) {
    const float* x   = (const float*)d_in[0];   // [M][K], fp16-valued f32
    const int*   w   = (const int*)d_in[1];     // [N][K] int32 (int8-valued)
    const float* wsc = (const float*)d_in[2];   // [N]
    float* out = (float*)d_out;                 // [M][N] (fp16-valued f32)

    const int K = K_DIM;
    const int M = in_sizes[0] / K;              // 8192
    const int N = N_DIM;

    int8_t* q   = (int8_t*)d_ws;                               // M*K  = 32 MB
    int8_t* w8  = (int8_t*)d_ws + (size_t)M * K;               // N*K  = 16 MB
    float*  asc = (float*)((char*)d_ws + (size_t)M * K + (size_t)N * K);

    quant_rows<<<M, 256, 0, stream>>>(x, q, asc);
    pack_w<<<(N * (K / 4)) / 256, 256, 0, stream>>>(w, w8);
    const int grid = (M / BM) * (N / BN);       // 512
    w8a8_gemm256<<<grid, 512, 131072, stream>>>(q, w8, asc, wsc, out, M);
}